// Round 2
// baseline (1450.795 us; speedup 1.0000x reference)
//
#include <hip/hip_runtime.h>
#include <stdint.h>
#include <math.h>

#define NN   100000
#define FIN  128
#define HIDDEN 256
#define NCLS 40
#define NE   1600000

typedef unsigned short u16;
typedef __attribute__((ext_vector_type(8))) short s16x8;
typedef __attribute__((ext_vector_type(4))) float f32x4;

__device__ __forceinline__ float bf2f(unsigned short u) {
    union { float f; uint32_t i; } v; v.i = ((uint32_t)u) << 16; return v.f;
}
__device__ __forceinline__ unsigned short f2bf(float f) {
    union { float f; uint32_t i; } v; v.f = f;
    uint32_t r = v.i + 0x7fffu + ((v.i >> 16) & 1u);
    return (unsigned short)(r >> 16);
}

// ---------------- dtype detection ----------------
// flags[0] != 0  => float tensors are stored as float32 (else bf16)
// flags[1] != 0  => edge_index stored as int64 (else int32)
__global__ void k_detect(const u16* __restrict__ x16, const int* __restrict__ ei,
                         int* __restrict__ flags) {
    int t = threadIdx.x;
    int nan_cnt = 0;
    for (int i = t; i < 65536; i += 256) {
        u16 v = x16[i] & 0x7fff;
        if (v >= 0x7f80) nan_cnt++;             // bf16 NaN/Inf bit pattern
    }
    int odd_nz = 0;
    for (int i = t; i < 8192; i += 256) {
        if (ei[2 * i + 1] != 0) odd_nz++;       // int64 high words are all 0
    }
    if (nan_cnt) atomicAdd(&flags[0], nan_cnt);
    if (odd_nz == 0) atomicAdd(&flags[1], 1);   // all-zero odd words in my slice
    // flags[1] final: if ANY thread saw a nonzero odd word, subtract below
    if (odd_nz) atomicAdd(&flags[2], 1);
}

__global__ void k_finalize_flags(int* flags) {
    if (threadIdx.x == 0 && blockIdx.x == 0) {
        flags[1] = (flags[2] == 0) ? 1 : 0;     // i64 iff no thread saw nonzero odd word
    }
}

// generic float-ish -> bf16 normalizer
__global__ void k_cvt(const void* __restrict__ src, u16* __restrict__ dst, int n,
                      const int* __restrict__ flags) {
    int i = blockIdx.x * 256 + threadIdx.x;
    if (i >= n) return;
    if (flags[0]) dst[i] = f2bf(((const float*)src)[i]);
    else          dst[i] = ((const u16*)src)[i];
}

// ---------------- preprocessing ----------------

__global__ void k_hist(const int* __restrict__ ei, int* __restrict__ cnt,
                       const int* __restrict__ flags) {
    int e = blockIdx.x * 256 + threadIdx.x;
    if (e < NE) {
        int d = flags[1] ? ei[2 * (NE + e)] : ei[NE + e];
        if ((unsigned)d < NN) atomicAdd(&cnt[d], 1);
    }
}

__global__ void k_dinv(const int* __restrict__ cnt, float* __restrict__ dinv) {
    int i = blockIdx.x * 256 + threadIdx.x;
    if (i < NN) dinv[i] = rsqrtf((float)(cnt[i] + 1));
}

__global__ __launch_bounds__(256) void k_scan1(const int* __restrict__ cnt,
                                               int* __restrict__ out,
                                               int* __restrict__ bsum) {
    __shared__ int sh[256];
    int t = threadIdx.x;
    int base = blockIdx.x * 1024 + t * 4;
    int v0 = 0, v1 = 0, v2 = 0, v3 = 0;
    if (base + 0 < NN) v0 = cnt[base + 0];
    if (base + 1 < NN) v1 = cnt[base + 1];
    if (base + 2 < NN) v2 = cnt[base + 2];
    if (base + 3 < NN) v3 = cnt[base + 3];
    int s = v0 + v1 + v2 + v3;
    sh[t] = s;
    __syncthreads();
    for (int off = 1; off < 256; off <<= 1) {
        int x = (t >= off) ? sh[t - off] : 0;
        __syncthreads();
        sh[t] += x;
        __syncthreads();
    }
    int ex = sh[t] - s;
    if (base + 0 < NN) out[base + 0] = ex;
    if (base + 1 < NN) out[base + 1] = ex + v0;
    if (base + 2 < NN) out[base + 2] = ex + v0 + v1;
    if (base + 3 < NN) out[base + 3] = ex + v0 + v1 + v2;
    if (t == 255) bsum[blockIdx.x] = sh[255];
}

__global__ void k_scan2(int* bsum, int nb) {
    if (threadIdx.x == 0 && blockIdx.x == 0) {
        int run = 0;
        for (int i = 0; i < nb; ++i) { int t = bsum[i]; bsum[i] = run; run += t; }
    }
}

__global__ void k_scan3(int* __restrict__ rp, const int* __restrict__ bsum,
                        int* __restrict__ pos) {
    int i = blockIdx.x * 256 + threadIdx.x;
    if (i < NN) {
        int v = rp[i] + bsum[i >> 10];
        rp[i] = v;
        pos[i] = v;
    }
    if (i == 0) rp[NN] = NE;
}

__global__ void k_fill(const int* __restrict__ ei, int* __restrict__ pos,
                       int* __restrict__ col, const int* __restrict__ flags) {
    int e = blockIdx.x * 256 + threadIdx.x;
    if (e < NE) {
        int i64 = flags[1];
        int d = i64 ? ei[2 * (NE + e)] : ei[NE + e];
        int s = i64 ? ei[2 * e]        : ei[e];
        if ((unsigned)d < NN && (unsigned)s < NN) {
            int q = atomicAdd(&pos[d], 1);
            col[q] = s;
        }
    }
}

// W [K,F] (f32 or bf16 per flags[0]) -> Wt [Fpad,K] bf16 (zero pad rows F..Fpad)
__global__ void k_transpose(const void* __restrict__ W, u16* __restrict__ Wt,
                            int K, int F, int Fpad, const int* __restrict__ flags) {
    int idx = blockIdx.x * 256 + threadIdx.x;
    if (idx >= K * Fpad) return;
    int f = idx / K, k = idx - f * K;
    u16 v = 0;
    if (f < F) {
        if (flags[0]) v = f2bf(((const float*)W)[(size_t)k * F + f]);
        else          v = ((const u16*)W)[(size_t)k * F + f];
    }
    Wt[idx] = v;
}

// ---------------- GEMM: C[row,col] = dinv[row] * (A[N,K] @ Wt[F,K]^T) ----------------
// BM=64, BN=64, BK=32; 256 threads = 4 waves (2x2 of 32x32), mfma 16x16x32 bf16.

#define LDT 40  // padded LDS row stride (elements)

__global__ __launch_bounds__(256) void k_gemm(const u16* __restrict__ A,
                                              const u16* __restrict__ Wt,
                                              const float* __restrict__ dinv,
                                              u16* __restrict__ C,
                                              int K, int Fstore) {
    __shared__ __align__(16) u16 As[64 * LDT];
    __shared__ __align__(16) u16 Bs[64 * LDT];
    int t = threadIdx.x;
    int bm = blockIdx.x, bn = blockIdx.y;
    int rowBase = bm * 64;
    int r = t >> 2;             // 0..63
    int cseg = (t & 3) * 8;     // 0,8,16,24
    int w = t >> 6;
    int wm = w >> 1, wn = w & 1;
    int lane = t & 63;
    int lrow = lane & 15;
    int lq = lane >> 4;         // 0..3
    f32x4 acc[2][2];
#pragma unroll
    for (int i = 0; i < 2; ++i)
#pragma unroll
        for (int j = 0; j < 2; ++j)
            acc[i][j] = (f32x4){0.f, 0.f, 0.f, 0.f};

    int nK = K >> 5;
    for (int kt = 0; kt < nK; ++kt) {
        int k0 = kt * 32;
        uint4 av = make_uint4(0, 0, 0, 0);
        int arow = rowBase + r;
        if (arow < NN) av = *(const uint4*)(A + (size_t)arow * K + k0 + cseg);
        *(uint4*)(As + r * LDT + cseg) = av;
        uint4 bv = *(const uint4*)(Wt + (size_t)(bn * 64 + r) * K + k0 + cseg);
        *(uint4*)(Bs + r * LDT + cseg) = bv;
        __syncthreads();

        s16x8 afr[2], bfr[2];
        afr[0] = *(const s16x8*)(As + (wm * 32 + lrow) * LDT + lq * 8);
        afr[1] = *(const s16x8*)(As + (wm * 32 + 16 + lrow) * LDT + lq * 8);
        bfr[0] = *(const s16x8*)(Bs + (wn * 32 + lrow) * LDT + lq * 8);
        bfr[1] = *(const s16x8*)(Bs + (wn * 32 + 16 + lrow) * LDT + lq * 8);
#pragma unroll
        for (int i = 0; i < 2; ++i)
#pragma unroll
            for (int j = 0; j < 2; ++j)
                acc[i][j] = __builtin_amdgcn_mfma_f32_16x16x32_bf16(afr[i], bfr[j], acc[i][j], 0, 0, 0);
        __syncthreads();
    }

#pragma unroll
    for (int ti = 0; ti < 2; ++ti)
#pragma unroll
        for (int tj = 0; tj < 2; ++tj)
#pragma unroll
            for (int rr = 0; rr < 4; ++rr) {
                int row = rowBase + wm * 32 + ti * 16 + lq * 4 + rr;
                int colg = bn * 64 + wn * 32 + tj * 16 + lrow;
                if (row < NN && colg < Fstore)
                    C[(size_t)row * Fstore + colg] = f2bf(acc[ti][tj][rr] * dinv[row]);
            }
}

// ---------------- aggregation F=256: act' = relu(dinv[row]*(sum hs[nbr] + hs[row]) + b)
__global__ __launch_bounds__(256) void k_agg(const u16* __restrict__ hs,
                                             const int* __restrict__ rp,
                                             const int* __restrict__ col,
                                             const float* __restrict__ dinv,
                                             const u16* __restrict__ bias,
                                             u16* __restrict__ out) {
    int row = blockIdx.x * 4 + (threadIdx.x >> 6);
    if (row >= NN) return;
    int lane = threadIdx.x & 63;
    int f = lane * 4;
    uint2 sv = *(const uint2*)(hs + (size_t)row * HIDDEN + f);
    float a0 = bf2f((u16)(sv.x & 0xffff));
    float a1 = bf2f((u16)(sv.x >> 16));
    float a2 = bf2f((u16)(sv.y & 0xffff));
    float a3 = bf2f((u16)(sv.y >> 16));
    int p1 = rp[row + 1];
    for (int p = rp[row]; p < p1; ++p) {
        int s = col[p];
        uint2 v = *(const uint2*)(hs + (size_t)s * HIDDEN + f);
        a0 += bf2f((u16)(v.x & 0xffff));
        a1 += bf2f((u16)(v.x >> 16));
        a2 += bf2f((u16)(v.y & 0xffff));
        a3 += bf2f((u16)(v.y >> 16));
    }
    float d = dinv[row];
    uint2 bv = *(const uint2*)(bias + f);
    a0 = fmaxf(fmaf(d, a0, bf2f((u16)(bv.x & 0xffff))), 0.f);
    a1 = fmaxf(fmaf(d, a1, bf2f((u16)(bv.x >> 16))), 0.f);
    a2 = fmaxf(fmaf(d, a2, bf2f((u16)(bv.y & 0xffff))), 0.f);
    a3 = fmaxf(fmaf(d, a3, bf2f((u16)(bv.y >> 16))), 0.f);
    uint2 o;
    o.x = (uint32_t)f2bf(a0) | ((uint32_t)f2bf(a1) << 16);
    o.y = (uint32_t)f2bf(a2) | ((uint32_t)f2bf(a3) << 16);
    *(uint2*)(out + (size_t)row * HIDDEN + f) = o;
}

// ---------------- last layer: aggregate F=40 + bias + log_softmax -> out (f32 or bf16)
__global__ __launch_bounds__(256) void k_agg5(const u16* __restrict__ hs,
                                              const int* __restrict__ rp,
                                              const int* __restrict__ col,
                                              const float* __restrict__ dinv,
                                              const u16* __restrict__ bias,
                                              void* __restrict__ out,
                                              const int* __restrict__ flags) {
    int row = blockIdx.x * 4 + (threadIdx.x >> 6);
    if (row >= NN) return;
    int lane = threadIdx.x & 63;
    bool act = lane < NCLS;
    float acc = 0.f;
    if (act) acc = bf2f(hs[(size_t)row * NCLS + lane]);
    int p1 = rp[row + 1];
    for (int p = rp[row]; p < p1; ++p) {
        int s = col[p];
        if (act) acc += bf2f(hs[(size_t)s * NCLS + lane]);
    }
    float logit = act ? fmaf(dinv[row], acc, bf2f(bias[lane])) : -1e30f;
    float m = logit;
#pragma unroll
    for (int off = 32; off > 0; off >>= 1) m = fmaxf(m, __shfl_xor(m, off));
    float e = act ? __expf(logit - m) : 0.f;
    float ssum = e;
#pragma unroll
    for (int off = 32; off > 0; off >>= 1) ssum += __shfl_xor(ssum, off);
    if (act) {
        float r = logit - m - __logf(ssum);
        size_t idx = (size_t)row * NCLS + lane;
        if (flags[0]) ((float*)out)[idx] = r;
        else          ((u16*)out)[idx]   = f2bf(r);
    }
}

// ---------------- launch ----------------

extern "C" void kernel_launch(void* const* d_in, const int* in_sizes, int n_in,
                              void* d_out, int out_size, void* d_ws, size_t ws_size,
                              hipStream_t stream) {
    const void* x  = d_in[0];
    const int* ei  = (const int*)d_in[1];
    const void* W1 = d_in[2];
    const void* b1 = d_in[3];
    const void* W2 = d_in[4];
    const void* b2 = d_in[5];
    const void* W3 = d_in[6];
    const void* b3 = d_in[7];
    const void* W4 = d_in[8];
    const void* b4 = d_in[9];

    char* p = (char*)d_ws;
    auto alloc = [&](size_t b) -> char* {
        char* r = p;
        p += (b + 255) & ~(size_t)255;
        return r;
    };
    int*   flags = (int*)alloc(256);
    int*   cnt  = (int*)alloc((size_t)NN * 4);
    float* dinv = (float*)alloc((size_t)NN * 4);
    int*   rp   = (int*)alloc((size_t)(NN + 1) * 4);
    int*   pos  = (int*)alloc((size_t)(NN + 1) * 4);
    int*   col  = (int*)alloc((size_t)NE * 4);
    int*   bsum = (int*)alloc(4096);
    u16* xb  = (u16*)alloc((size_t)NN * FIN * 2);
    u16* W1t = (u16*)alloc((size_t)256 * 128 * 2);
    u16* W2t = (u16*)alloc((size_t)256 * 256 * 2);
    u16* W3t = (u16*)alloc((size_t)256 * 256 * 2);
    u16* W4t = (u16*)alloc((size_t)64 * 256 * 2);
    u16* bb1 = (u16*)alloc(512);
    u16* bb2 = (u16*)alloc(512);
    u16* bb3 = (u16*)alloc(512);
    u16* bb4 = (u16*)alloc(128);
    u16* bufA = (u16*)alloc((size_t)NN * HIDDEN * 2);
    u16* bufB = (u16*)alloc((size_t)NN * HIDDEN * 2);

    hipMemsetAsync(flags, 0, 256, stream);
    hipMemsetAsync(cnt, 0, (size_t)NN * 4, stream);
    k_detect<<<1, 256, 0, stream>>>((const u16*)x, ei, flags);
    k_finalize_flags<<<1, 64, 0, stream>>>(flags);

    // normalize inputs to bf16 / build CSR
    k_cvt<<<(NN * FIN + 255) / 256, 256, 0, stream>>>(x, xb, NN * FIN, flags);
    k_cvt<<<1, 256, 0, stream>>>(b1, bb1, 256, flags);
    k_cvt<<<1, 256, 0, stream>>>(b2, bb2, 256, flags);
    k_cvt<<<1, 256, 0, stream>>>(b3, bb3, 256, flags);
    k_cvt<<<1, 256, 0, stream>>>(b4, bb4, NCLS, flags);
    k_transpose<<<(128 * 256 + 255) / 256, 256, 0, stream>>>(W1, W1t, 128, 256, 256, flags);
    k_transpose<<<(256 * 256 + 255) / 256, 256, 0, stream>>>(W2, W2t, 256, 256, 256, flags);
    k_transpose<<<(256 * 256 + 255) / 256, 256, 0, stream>>>(W3, W3t, 256, 256, 256, flags);
    k_transpose<<<(256 * 64 + 255) / 256, 256, 0, stream>>>(W4, W4t, 256, 40, 64, flags);

    k_hist<<<(NE + 255) / 256, 256, 0, stream>>>(ei, cnt, flags);
    k_dinv<<<(NN + 255) / 256, 256, 0, stream>>>(cnt, dinv);
    k_scan1<<<(NN + 1023) / 1024, 256, 0, stream>>>(cnt, rp, bsum);
    k_scan2<<<1, 64, 0, stream>>>(bsum, (NN + 1023) / 1024);
    k_scan3<<<(NN + 255) / 256, 256, 0, stream>>>(rp, bsum, pos);
    k_fill<<<(NE + 255) / 256, 256, 0, stream>>>(ei, pos, col, flags);

    dim3 gemmGrid((NN + 63) / 64, 4);
    dim3 aggGrid((NN + 3) / 4);

    // conv1: x @ W1
    k_gemm<<<gemmGrid, 256, 0, stream>>>(xb, W1t, dinv, bufB, 128, 256);
    k_agg<<<aggGrid, 256, 0, stream>>>(bufB, rp, col, dinv, bb1, bufA);
    // conv2: @ W2
    k_gemm<<<gemmGrid, 256, 0, stream>>>(bufA, W2t, dinv, bufB, 256, 256);
    k_agg<<<aggGrid, 256, 0, stream>>>(bufB, rp, col, dinv, bb2, bufA);
    // conv3: @ W2 (reused)
    k_gemm<<<gemmGrid, 256, 0, stream>>>(bufA, W2t, dinv, bufB, 256, 256);
    k_agg<<<aggGrid, 256, 0, stream>>>(bufB, rp, col, dinv, bb2, bufA);
    // conv4: @ W3
    k_gemm<<<gemmGrid, 256, 0, stream>>>(bufA, W3t, dinv, bufB, 256, 256);
    k_agg<<<aggGrid, 256, 0, stream>>>(bufB, rp, col, dinv, bb3, bufA);
    // conv5: @ W4 (Fpad=64, store F=40) + fused log_softmax
    dim3 g5((NN + 63) / 64, 1);
    k_gemm<<<g5, 256, 0, stream>>>(bufA, W4t, dinv, bufB, 256, 40);
    k_agg5<<<aggGrid, 256, 0, stream>>>(bufB, rp, col, dinv, bb4, d_out, flags);
}

// Round 3
// 1140.845 us; speedup vs baseline: 1.2717x; 1.2717x over previous
//
#include <hip/hip_runtime.h>
#include <stdint.h>
#include <math.h>

#define NN   100000
#define FIN  128
#define HIDDEN 256
#define NCLS 40
#define NE   1600000

typedef unsigned short u16;
typedef __attribute__((ext_vector_type(8))) short s16x8;
typedef __attribute__((ext_vector_type(4))) float f32x4;

__device__ __forceinline__ float bf2f(unsigned short u) {
    union { float f; uint32_t i; } v; v.i = ((uint32_t)u) << 16; return v.f;
}
__device__ __forceinline__ unsigned short f2bf(float f) {
    union { float f; uint32_t i; } v; v.f = f;
    uint32_t r = v.i + 0x7fffu + ((v.i >> 16) & 1u);
    return (unsigned short)(r >> 16);
}

// ---------------- dtype detection ----------------
// flags[0] != 0 => float tensors are float32 (else bf16); flags[1] != 0 => edge_index int64
__global__ void k_detect(const u16* __restrict__ x16, const int* __restrict__ ei,
                         int* __restrict__ flags) {
    int t = threadIdx.x;
    int nan_cnt = 0;
    for (int i = t; i < 65536; i += 256) {
        u16 v = x16[i] & 0x7fff;
        if (v >= 0x7f80) nan_cnt++;
    }
    int odd_nz = 0;
    for (int i = t; i < 8192; i += 256) {
        if (ei[2 * i + 1] != 0) odd_nz++;
    }
    if (nan_cnt) atomicAdd(&flags[0], nan_cnt);
    if (odd_nz) atomicAdd(&flags[2], 1);
}

__global__ void k_finalize_flags(int* flags) {
    if (threadIdx.x == 0 && blockIdx.x == 0) flags[1] = (flags[2] == 0) ? 1 : 0;
}

__global__ void k_cvt(const void* __restrict__ src, u16* __restrict__ dst, int n,
                      const int* __restrict__ flags) {
    int i = blockIdx.x * 256 + threadIdx.x;
    if (i >= n) return;
    if (flags[0]) dst[i] = f2bf(((const float*)src)[i]);
    else          dst[i] = ((const u16*)src)[i];
}

__global__ void k_cvt_bias(const void* b1, const void* b2, const void* b3, const void* b4,
                           u16* o1, u16* o2, u16* o3, u16* o4,
                           const int* __restrict__ flags) {
    int t = threadIdx.x;
    int fl = flags[0];
    if (t < 256) o1[t] = fl ? f2bf(((const float*)b1)[t]) : ((const u16*)b1)[t];
    if (t < 256) o2[t] = fl ? f2bf(((const float*)b2)[t]) : ((const u16*)b2)[t];
    if (t < 256) o3[t] = fl ? f2bf(((const float*)b3)[t]) : ((const u16*)b3)[t];
    if (t < NCLS) o4[t] = fl ? f2bf(((const float*)b4)[t]) : ((const u16*)b4)[t];
}

// all four W [K,F] -> Wt [Fpad,K] bf16 in one launch
__global__ void k_transpose_all(const void* W1, const void* W2, const void* W3, const void* W4,
                                u16* W1t, u16* W2t, u16* W3t, u16* W4t,
                                const int* __restrict__ flags) {
    int b = blockIdx.x;
    const void* W; u16* Wt; int K, F, Fpad, base;
    if (b < 128)      { W = W1; Wt = W1t; K = 128; F = 256; Fpad = 256; base = 0; }
    else if (b < 384) { W = W2; Wt = W2t; K = 256; F = 256; Fpad = 256; base = 128; }
    else if (b < 640) { W = W3; Wt = W3t; K = 256; F = 256; Fpad = 256; base = 384; }
    else              { W = W4; Wt = W4t; K = 256; F = 40;  Fpad = 64;  base = 640; }
    int idx = (b - base) * 256 + threadIdx.x;
    if (idx >= K * Fpad) return;
    int f = idx / K, k = idx - f * K;
    u16 v = 0;
    if (f < F) {
        if (flags[0]) v = f2bf(((const float*)W)[(size_t)k * F + f]);
        else          v = ((const u16*)W)[(size_t)k * F + f];
    }
    Wt[idx] = v;
}

// ---------------- CSR build ----------------

__global__ void k_hist(const int* __restrict__ ei, int* __restrict__ cnt,
                       const int* __restrict__ flags) {
    int e = blockIdx.x * 256 + threadIdx.x;
    if (e < NE) {
        int d = flags[1] ? ei[2 * (NE + e)] : ei[NE + e];
        if ((unsigned)d < NN) atomicAdd(&cnt[d], 1);
    }
}

__global__ __launch_bounds__(256) void k_scan1(const int* __restrict__ cnt,
                                               int* __restrict__ out,
                                               int* __restrict__ bsum) {
    __shared__ int sh[256];
    int t = threadIdx.x;
    int base = blockIdx.x * 1024 + t * 4;
    int v0 = 0, v1 = 0, v2 = 0, v3 = 0;
    if (base + 0 < NN) v0 = cnt[base + 0];
    if (base + 1 < NN) v1 = cnt[base + 1];
    if (base + 2 < NN) v2 = cnt[base + 2];
    if (base + 3 < NN) v3 = cnt[base + 3];
    int s = v0 + v1 + v2 + v3;
    sh[t] = s;
    __syncthreads();
    for (int off = 1; off < 256; off <<= 1) {
        int x = (t >= off) ? sh[t - off] : 0;
        __syncthreads();
        sh[t] += x;
        __syncthreads();
    }
    int ex = sh[t] - s;
    if (base + 0 < NN) out[base + 0] = ex;
    if (base + 1 < NN) out[base + 1] = ex + v0;
    if (base + 2 < NN) out[base + 2] = ex + v0 + v1;
    if (base + 3 < NN) out[base + 3] = ex + v0 + v1 + v2;
    if (t == 255) bsum[blockIdx.x] = sh[255];
}

__global__ void k_scan2(int* bsum, int nb) {
    if (threadIdx.x == 0 && blockIdx.x == 0) {
        int run = 0;
        for (int i = 0; i < nb; ++i) { int t = bsum[i]; bsum[i] = run; run += t; }
    }
}

// also computes dinv
__global__ void k_scan3(int* __restrict__ rp, const int* __restrict__ bsum,
                        int* __restrict__ pos, const int* __restrict__ cnt,
                        float* __restrict__ dinv) {
    int i = blockIdx.x * 256 + threadIdx.x;
    if (i < NN) {
        int v = rp[i] + bsum[i >> 10];
        rp[i] = v;
        pos[i] = v;
        dinv[i] = rsqrtf((float)(cnt[i] + 1));
    }
    if (i == 0) rp[NN] = NE;
}

__global__ void k_fill(const int* __restrict__ ei, int* __restrict__ pos,
                       int* __restrict__ col, const int* __restrict__ flags) {
    int e = blockIdx.x * 256 + threadIdx.x;
    if (e < NE) {
        int i64 = flags[1];
        int d = i64 ? ei[2 * (NE + e)] : ei[NE + e];
        int s = i64 ? ei[2 * e]        : ei[e];
        if ((unsigned)d < NN && (unsigned)s < NN) {
            int q = atomicAdd(&pos[d], 1);
            col[q] = s;
        }
    }
}

// ---------------- GEMM 128x128 (m97 structure): C = dinv[row]*(A@Wt^T) ----------------
// 256 threads = 4 waves (2x2), each wave 64x64 via 4x4 of mfma 16x16x32.
// Staging: global_load_lds width-16, LDS row-major [128][32] contiguous.

#define GLL(g, l) __builtin_amdgcn_global_load_lds( \
    (const __attribute__((address_space(1))) unsigned int*)(g), \
    (__attribute__((address_space(3))) unsigned int*)(l), 16, 0, 0)

__global__ __launch_bounds__(256) void k_gemm128(const u16* __restrict__ A,
                                                 const u16* __restrict__ Wt,
                                                 const float* __restrict__ dinv,
                                                 u16* __restrict__ C,
                                                 int K) {
    __shared__ __align__(16) u16 As[128 * 32];
    __shared__ __align__(16) u16 Bs[128 * 32];
    int t = threadIdx.x;
    int bm = blockIdx.x, bn = blockIdx.y;
    int rowBase = bm * 128;
    int w = t >> 6, lane = t & 63;
    int wm = w >> 1, wn = w & 1;
    int lrow = lane & 15, lq = lane >> 4;

    f32x4 acc[4][4] = {};

    int r0 = t >> 2;            // 0..63
    int seg = (t & 3) * 8;      // k-element offset (0,8,16,24)
    int ar0 = rowBase + r0;       if (ar0 > NN - 1) ar0 = NN - 1;
    int ar1 = rowBase + 64 + r0;  if (ar1 > NN - 1) ar1 = NN - 1;
    const u16* a0p = A + (size_t)ar0 * K + seg;
    const u16* a1p = A + (size_t)ar1 * K + seg;
    const u16* b0p = Wt + (size_t)(bn * 128 + r0) * K + seg;
    const u16* b1p = Wt + (size_t)(bn * 128 + 64 + r0) * K + seg;
    u16* As0 = As + t * 8;
    u16* As1 = As + 2048 + t * 8;
    u16* Bs0 = Bs + t * 8;
    u16* Bs1 = Bs + 2048 + t * 8;

    int nK = K >> 5;
    for (int kt = 0; kt < nK; ++kt) {
        GLL(a0p, As0);
        GLL(a1p, As1);
        GLL(b0p, Bs0);
        GLL(b1p, Bs1);
        a0p += 32; a1p += 32; b0p += 32; b1p += 32;
        __syncthreads();
        s16x8 af[4], bf[4];
#pragma unroll
        for (int i = 0; i < 4; ++i)
            af[i] = *(const s16x8*)(As + (wm * 64 + i * 16 + lrow) * 32 + lq * 8);
#pragma unroll
        for (int j = 0; j < 4; ++j)
            bf[j] = *(const s16x8*)(Bs + (wn * 64 + j * 16 + lrow) * 32 + lq * 8);
#pragma unroll
        for (int i = 0; i < 4; ++i)
#pragma unroll
            for (int j = 0; j < 4; ++j)
                acc[i][j] = __builtin_amdgcn_mfma_f32_16x16x32_bf16(af[i], bf[j], acc[i][j], 0, 0, 0);
        __syncthreads();
    }

#pragma unroll
    for (int i = 0; i < 4; ++i) {
#pragma unroll
        for (int rr = 0; rr < 4; ++rr) {
            int row = rowBase + wm * 64 + i * 16 + lq * 4 + rr;
            if (row < NN) {
                float d = dinv[row];
#pragma unroll
                for (int j = 0; j < 4; ++j) {
                    int colg = bn * 128 + wn * 64 + j * 16 + lrow;
                    C[(size_t)row * HIDDEN + colg] = f2bf(acc[i][j][rr] * d);
                }
            }
        }
    }
}

// ---------------- GEMM 64x64 (for conv5, N<=64) ----------------
#define LDT 40

__global__ __launch_bounds__(256) void k_gemm64(const u16* __restrict__ A,
                                                const u16* __restrict__ Wt,
                                                const float* __restrict__ dinv,
                                                u16* __restrict__ C,
                                                int K, int Fstore) {
    __shared__ __align__(16) u16 As[64 * LDT];
    __shared__ __align__(16) u16 Bs[64 * LDT];
    int t = threadIdx.x;
    int bm = blockIdx.x, bn = blockIdx.y;
    int rowBase = bm * 64;
    int r = t >> 2;
    int cseg = (t & 3) * 8;
    int w = t >> 6;
    int wm = w >> 1, wn = w & 1;
    int lane = t & 63;
    int lrow = lane & 15;
    int lq = lane >> 4;
    f32x4 acc[2][2] = {};

    int nK = K >> 5;
    for (int kt = 0; kt < nK; ++kt) {
        int k0 = kt * 32;
        uint4 av = make_uint4(0, 0, 0, 0);
        int arow = rowBase + r;
        if (arow < NN) av = *(const uint4*)(A + (size_t)arow * K + k0 + cseg);
        *(uint4*)(As + r * LDT + cseg) = av;
        uint4 bv = *(const uint4*)(Wt + (size_t)(bn * 64 + r) * K + k0 + cseg);
        *(uint4*)(Bs + r * LDT + cseg) = bv;
        __syncthreads();

        s16x8 afr[2], bfr[2];
        afr[0] = *(const s16x8*)(As + (wm * 32 + lrow) * LDT + lq * 8);
        afr[1] = *(const s16x8*)(As + (wm * 32 + 16 + lrow) * LDT + lq * 8);
        bfr[0] = *(const s16x8*)(Bs + (wn * 32 + lrow) * LDT + lq * 8);
        bfr[1] = *(const s16x8*)(Bs + (wn * 32 + 16 + lrow) * LDT + lq * 8);
#pragma unroll
        for (int i = 0; i < 2; ++i)
#pragma unroll
            for (int j = 0; j < 2; ++j)
                acc[i][j] = __builtin_amdgcn_mfma_f32_16x16x32_bf16(afr[i], bfr[j], acc[i][j], 0, 0, 0);
        __syncthreads();
    }

#pragma unroll
    for (int ti = 0; ti < 2; ++ti)
#pragma unroll
        for (int tj = 0; tj < 2; ++tj)
#pragma unroll
            for (int rr = 0; rr < 4; ++rr) {
                int row = rowBase + wm * 32 + ti * 16 + lq * 4 + rr;
                int colg = bn * 64 + wn * 32 + tj * 16 + lrow;
                if (row < NN && colg < Fstore)
                    C[(size_t)row * Fstore + colg] = f2bf(acc[ti][tj][rr] * dinv[row]);
            }
}

// ---------------- aggregation F=256 ----------------
// one wave per row; half-wave per edge (2 edges in flight), uint4 loads, 2x unroll.

__device__ __forceinline__ void acc8(float* a, uint4 v) {
    a[0] += bf2f((u16)(v.x & 0xffff)); a[1] += bf2f((u16)(v.x >> 16));
    a[2] += bf2f((u16)(v.y & 0xffff)); a[3] += bf2f((u16)(v.y >> 16));
    a[4] += bf2f((u16)(v.z & 0xffff)); a[5] += bf2f((u16)(v.z >> 16));
    a[6] += bf2f((u16)(v.w & 0xffff)); a[7] += bf2f((u16)(v.w >> 16));
}

__global__ __launch_bounds__(256) void k_agg(const u16* __restrict__ hs,
                                             const int* __restrict__ rp,
                                             const int* __restrict__ col,
                                             const float* __restrict__ dinv,
                                             const u16* __restrict__ bias,
                                             u16* __restrict__ out) {
    int row = blockIdx.x * 4 + (threadIdx.x >> 6);
    if (row >= NN) return;
    int lane = threadIdx.x & 63;
    int half = lane >> 5;
    int fb = (lane & 31) * 8;
    float a[8] = {0.f, 0.f, 0.f, 0.f, 0.f, 0.f, 0.f, 0.f};
    if (half == 0) acc8(a, *(const uint4*)(hs + (size_t)row * HIDDEN + fb));
    int p = rp[row] + half, p1 = rp[row + 1];
    for (; p + 2 < p1; p += 4) {
        int s0 = col[p], s1 = col[p + 2];
        uint4 v0 = *(const uint4*)(hs + (size_t)s0 * HIDDEN + fb);
        uint4 v1 = *(const uint4*)(hs + (size_t)s1 * HIDDEN + fb);
        acc8(a, v0);
        acc8(a, v1);
    }
    if (p < p1) {
        int s = col[p];
        acc8(a, *(const uint4*)(hs + (size_t)s * HIDDEN + fb));
    }
#pragma unroll
    for (int i = 0; i < 8; ++i) a[i] += __shfl_xor(a[i], 32);
    if (half == 0) {
        float d = dinv[row];
        uint4 bv = *(const uint4*)(bias + fb);
        float r0 = fmaxf(fmaf(d, a[0], bf2f((u16)(bv.x & 0xffff))), 0.f);
        float r1 = fmaxf(fmaf(d, a[1], bf2f((u16)(bv.x >> 16))), 0.f);
        float r2 = fmaxf(fmaf(d, a[2], bf2f((u16)(bv.y & 0xffff))), 0.f);
        float r3 = fmaxf(fmaf(d, a[3], bf2f((u16)(bv.y >> 16))), 0.f);
        float r4 = fmaxf(fmaf(d, a[4], bf2f((u16)(bv.z & 0xffff))), 0.f);
        float r5 = fmaxf(fmaf(d, a[5], bf2f((u16)(bv.z >> 16))), 0.f);
        float r6 = fmaxf(fmaf(d, a[6], bf2f((u16)(bv.w & 0xffff))), 0.f);
        float r7 = fmaxf(fmaf(d, a[7], bf2f((u16)(bv.w >> 16))), 0.f);
        uint4 o;
        o.x = (uint32_t)f2bf(r0) | ((uint32_t)f2bf(r1) << 16);
        o.y = (uint32_t)f2bf(r2) | ((uint32_t)f2bf(r3) << 16);
        o.z = (uint32_t)f2bf(r4) | ((uint32_t)f2bf(r5) << 16);
        o.w = (uint32_t)f2bf(r6) | ((uint32_t)f2bf(r7) << 16);
        *(uint4*)(out + (size_t)row * HIDDEN + fb) = o;
    }
}

// ---------------- last layer: aggregate F=40 + bias + log_softmax ----------------
__global__ __launch_bounds__(256) void k_agg5(const u16* __restrict__ hs,
                                              const int* __restrict__ rp,
                                              const int* __restrict__ col,
                                              const float* __restrict__ dinv,
                                              const u16* __restrict__ bias,
                                              void* __restrict__ out,
                                              const int* __restrict__ flags) {
    int row = blockIdx.x * 4 + (threadIdx.x >> 6);
    if (row >= NN) return;
    int lane = threadIdx.x & 63;
    bool act = lane < NCLS;
    float acc = 0.f;
    if (act) acc = bf2f(hs[(size_t)row * NCLS + lane]);
    int p = rp[row], p1 = rp[row + 1];
    for (; p + 1 < p1; p += 2) {
        int s0 = col[p], s1 = col[p + 1];
        if (act) {
            float v0 = bf2f(hs[(size_t)s0 * NCLS + lane]);
            float v1 = bf2f(hs[(size_t)s1 * NCLS + lane]);
            acc += v0 + v1;
        }
    }
    if (p < p1) {
        int s = col[p];
        if (act) acc += bf2f(hs[(size_t)s * NCLS + lane]);
    }
    float logit = act ? fmaf(dinv[row], acc, bf2f(bias[lane])) : -1e30f;
    float m = logit;
#pragma unroll
    for (int off = 32; off > 0; off >>= 1) m = fmaxf(m, __shfl_xor(m, off));
    float e = act ? __expf(logit - m) : 0.f;
    float ssum = e;
#pragma unroll
    for (int off = 32; off > 0; off >>= 1) ssum += __shfl_xor(ssum, off);
    if (act) {
        float r = logit - m - __logf(ssum);
        size_t idx = (size_t)row * NCLS + lane;
        if (flags[0]) ((float*)out)[idx] = r;
        else          ((u16*)out)[idx]   = f2bf(r);
    }
}

// ---------------- launch ----------------

extern "C" void kernel_launch(void* const* d_in, const int* in_sizes, int n_in,
                              void* d_out, int out_size, void* d_ws, size_t ws_size,
                              hipStream_t stream) {
    const void* x  = d_in[0];
    const int* ei  = (const int*)d_in[1];
    const void* W1 = d_in[2];
    const void* b1 = d_in[3];
    const void* W2 = d_in[4];
    const void* b2 = d_in[5];
    const void* W3 = d_in[6];
    const void* b3 = d_in[7];
    const void* W4 = d_in[8];
    const void* b4 = d_in[9];

    char* p = (char*)d_ws;
    auto alloc = [&](size_t b) -> char* {
        char* r = p;
        p += (b + 255) & ~(size_t)255;
        return r;
    };
    int*   flags = (int*)alloc(256);
    int*   cnt  = (int*)alloc((size_t)NN * 4);
    float* dinv = (float*)alloc((size_t)NN * 4);
    int*   rp   = (int*)alloc((size_t)(NN + 1) * 4);
    int*   pos  = (int*)alloc((size_t)(NN + 1) * 4);
    int*   col  = (int*)alloc((size_t)NE * 4);
    int*   bsum = (int*)alloc(4096);
    u16* xb  = (u16*)alloc((size_t)NN * FIN * 2);
    u16* W1t = (u16*)alloc((size_t)256 * 128 * 2);
    u16* W2t = (u16*)alloc((size_t)256 * 256 * 2);
    u16* W3t = (u16*)alloc((size_t)256 * 256 * 2);
    u16* W4t = (u16*)alloc((size_t)64 * 256 * 2);
    u16* bb1 = (u16*)alloc(512);
    u16* bb2 = (u16*)alloc(512);
    u16* bb3 = (u16*)alloc(512);
    u16* bb4 = (u16*)alloc(128);
    u16* bufA = (u16*)alloc((size_t)NN * HIDDEN * 2);
    u16* bufB = (u16*)alloc((size_t)NN * HIDDEN * 2);

    hipMemsetAsync(flags, 0, 256, stream);
    hipMemsetAsync(cnt, 0, (size_t)NN * 4, stream);
    k_detect<<<1, 256, 0, stream>>>((const u16*)x, ei, flags);
    k_finalize_flags<<<1, 64, 0, stream>>>(flags);

    k_cvt<<<(NN * FIN + 255) / 256, 256, 0, stream>>>(x, xb, NN * FIN, flags);
    k_cvt_bias<<<1, 256, 0, stream>>>(b1, b2, b3, b4, bb1, bb2, bb3, bb4, flags);
    k_transpose_all<<<704, 256, 0, stream>>>(W1, W2, W3, W4, W1t, W2t, W3t, W4t, flags);

    k_hist<<<(NE + 255) / 256, 256, 0, stream>>>(ei, cnt, flags);
    k_scan1<<<(NN + 1023) / 1024, 256, 0, stream>>>(cnt, rp, bsum);
    k_scan2<<<1, 64, 0, stream>>>(bsum, (NN + 1023) / 1024);
    k_scan3<<<(NN + 255) / 256, 256, 0, stream>>>(rp, bsum, pos, cnt, dinv);
    k_fill<<<(NE + 255) / 256, 256, 0, stream>>>(ei, pos, col, flags);

    dim3 g128((NN + 127) / 128, 2);
    dim3 aggGrid((NN + 3) / 4);

    // conv1: x @ W1 (K=128)
    k_gemm128<<<g128, 256, 0, stream>>>(xb, W1t, dinv, bufB, 128);
    k_agg<<<aggGrid, 256, 0, stream>>>(bufB, rp, col, dinv, bb1, bufA);
    // conv2: @ W2
    k_gemm128<<<g128, 256, 0, stream>>>(bufA, W2t, dinv, bufB, 256);
    k_agg<<<aggGrid, 256, 0, stream>>>(bufB, rp, col, dinv, bb2, bufA);
    // conv3: @ W2 (reused)
    k_gemm128<<<g128, 256, 0, stream>>>(bufA, W2t, dinv, bufB, 256);
    k_agg<<<aggGrid, 256, 0, stream>>>(bufB, rp, col, dinv, bb2, bufA);
    // conv4: @ W3
    k_gemm128<<<g128, 256, 0, stream>>>(bufA, W3t, dinv, bufB, 256);
    k_agg<<<aggGrid, 256, 0, stream>>>(bufB, rp, col, dinv, bb3, bufA);
    // conv5: @ W4 (Fpad=64, store 40) + fused log_softmax
    dim3 g64((NN + 63) / 64, 1);
    k_gemm64<<<g64, 256, 0, stream>>>(bufA, W4t, dinv, bufB, 256, 40);
    k_agg5<<<aggGrid, 256, 0, stream>>>(bufB, rp, col, dinv, bb4, d_out, flags);
}

// Round 4
// 1041.366 us; speedup vs baseline: 1.3932x; 1.0955x over previous
//
#include <hip/hip_runtime.h>
#include <stdint.h>
#include <math.h>

#define NN   100000
#define FIN  128
#define HIDDEN 256
#define NCLS 40
#define NE   1600000

// CSR bucketing: P node-ranges x S edge-slices
#define PRNG 8
#define RNG  12500          // NN / PRNG
#define SSL  32
#define NES  50000          // NE / SSL

typedef unsigned short u16;
typedef __attribute__((ext_vector_type(8))) short s16x8;
typedef __attribute__((ext_vector_type(4))) float f32x4;

__device__ __forceinline__ float bf2f(unsigned short u) {
    union { float f; uint32_t i; } v; v.i = ((uint32_t)u) << 16; return v.f;
}
__device__ __forceinline__ unsigned short f2bf(float f) {
    union { float f; uint32_t i; } v; v.f = f;
    uint32_t r = v.i + 0x7fffu + ((v.i >> 16) & 1u);
    return (unsigned short)(r >> 16);
}

// ---------------- dtype detection ----------------
// flags[0] != 0 => float tensors are float32 (else bf16); flags[1] != 0 => edge_index int64
__global__ void k_detect(const u16* __restrict__ x16, const int* __restrict__ ei,
                         int* __restrict__ flags) {
    int t = threadIdx.x;
    int nan_cnt = 0;
    for (int i = t; i < 65536; i += 256) {
        u16 v = x16[i] & 0x7fff;
        if (v >= 0x7f80) nan_cnt++;
    }
    int odd_nz = 0;
    for (int i = t; i < 8192; i += 256) {
        if (ei[2 * i + 1] != 0) odd_nz++;
    }
    if (nan_cnt) atomicAdd(&flags[0], nan_cnt);
    if (odd_nz) atomicAdd(&flags[2], 1);
}

__global__ void k_finalize_flags(int* flags) {
    if (threadIdx.x == 0 && blockIdx.x == 0) flags[1] = (flags[2] == 0) ? 1 : 0;
}

__global__ void k_cvt(const void* __restrict__ src, u16* __restrict__ dst, int n,
                      const int* __restrict__ flags) {
    int i = blockIdx.x * 256 + threadIdx.x;
    if (i >= n) return;
    if (flags[0]) dst[i] = f2bf(((const float*)src)[i]);
    else          dst[i] = ((const u16*)src)[i];
}

__global__ void k_cvt_bias(const void* b1, const void* b2, const void* b3, const void* b4,
                           u16* o1, u16* o2, u16* o3, u16* o4,
                           const int* __restrict__ flags) {
    int t = threadIdx.x;
    int fl = flags[0];
    o1[t] = fl ? f2bf(((const float*)b1)[t]) : ((const u16*)b1)[t];
    o2[t] = fl ? f2bf(((const float*)b2)[t]) : ((const u16*)b2)[t];
    o3[t] = fl ? f2bf(((const float*)b3)[t]) : ((const u16*)b3)[t];
    if (t < NCLS) o4[t] = fl ? f2bf(((const float*)b4)[t]) : ((const u16*)b4)[t];
}

// all four W [K,F] -> Wt [Fpad,K] bf16 in one launch
__global__ void k_transpose_all(const void* W1, const void* W2, const void* W3, const void* W4,
                                u16* W1t, u16* W2t, u16* W3t, u16* W4t,
                                const int* __restrict__ flags) {
    int b = blockIdx.x;
    const void* W; u16* Wt; int K, F, Fpad, base;
    if (b < 128)      { W = W1; Wt = W1t; K = 128; F = 256; Fpad = 256; base = 0; }
    else if (b < 384) { W = W2; Wt = W2t; K = 256; F = 256; Fpad = 256; base = 128; }
    else if (b < 640) { W = W3; Wt = W3t; K = 256; F = 256; Fpad = 256; base = 384; }
    else              { W = W4; Wt = W4t; K = 256; F = 40;  Fpad = 64;  base = 640; }
    int idx = (b - base) * 256 + threadIdx.x;
    if (idx >= K * Fpad) return;
    int f = idx / K, k = idx - f * K;
    u16 v = 0;
    if (f < F) {
        if (flags[0]) v = f2bf(((const float*)W)[(size_t)k * F + f]);
        else          v = ((const u16*)W)[(size_t)k * F + f];
    }
    Wt[idx] = v;
}

// ---------------- CSR build (no device atomics) ----------------

__global__ void k_compact(const int* __restrict__ ei, int* __restrict__ dst32,
                          int* __restrict__ src32, const int* __restrict__ flags) {
    int e = blockIdx.x * 256 + threadIdx.x;
    if (e < NE) {
        if (flags[1]) { src32[e] = ei[2 * e]; dst32[e] = ei[2 * (NE + e)]; }
        else          { src32[e] = ei[e];     dst32[e] = ei[NE + e]; }
    }
}

// grid = PRNG*SSL blocks; block (p,s) histograms slice s for node range p in LDS
__global__ __launch_bounds__(256) void k_histb(const int* __restrict__ dst32,
                                               int* __restrict__ partial) {
    __shared__ int h[RNG];
    int p = blockIdx.x >> 5, s = blockIdx.x & 31;
    int t = threadIdx.x;
    int4 z4 = make_int4(0, 0, 0, 0);
    for (int i = t * 4; i < RNG; i += 1024) *(int4*)(h + i) = z4;
    __syncthreads();
    int base = s * NES;
    int lo = p * RNG;
    int nfull = NES & ~1023;
    for (int k = t * 4; k < nfull; k += 1024) {
        int4 d4 = *(const int4*)(dst32 + base + k);
        int a;
        a = d4.x - lo; if ((unsigned)a < RNG) atomicAdd(&h[a], 1);
        a = d4.y - lo; if ((unsigned)a < RNG) atomicAdd(&h[a], 1);
        a = d4.z - lo; if ((unsigned)a < RNG) atomicAdd(&h[a], 1);
        a = d4.w - lo; if ((unsigned)a < RNG) atomicAdd(&h[a], 1);
    }
    for (int k = nfull + t; k < NES; k += 256) {
        int a = dst32[base + k] - lo;
        if ((unsigned)a < RNG) atomicAdd(&h[a], 1);
    }
    __syncthreads();
    int* out = partial + blockIdx.x * RNG;
    for (int i = t * 4; i < RNG; i += 1024) *(int4*)(out + i) = *(const int4*)(h + i);
}

__global__ void k_sumpart(const int* __restrict__ partial, int* __restrict__ cnt) {
    int i = blockIdx.x * 256 + threadIdx.x;
    if (i >= NN) return;
    int p = i / RNG, il = i - p * RNG;
    const int* q = partial + (p * SSL) * RNG + il;
    int sum = 0;
#pragma unroll
    for (int s = 0; s < SSL; ++s) sum += q[s * RNG];
    cnt[i] = sum;
}

__global__ __launch_bounds__(256) void k_scan1(const int* __restrict__ cnt,
                                               int* __restrict__ out,
                                               int* __restrict__ bsum) {
    __shared__ int sh[256];
    int t = threadIdx.x;
    int base = blockIdx.x * 1024 + t * 4;
    int v0 = 0, v1 = 0, v2 = 0, v3 = 0;
    if (base + 0 < NN) v0 = cnt[base + 0];
    if (base + 1 < NN) v1 = cnt[base + 1];
    if (base + 2 < NN) v2 = cnt[base + 2];
    if (base + 3 < NN) v3 = cnt[base + 3];
    int s = v0 + v1 + v2 + v3;
    sh[t] = s;
    __syncthreads();
    for (int off = 1; off < 256; off <<= 1) {
        int x = (t >= off) ? sh[t - off] : 0;
        __syncthreads();
        sh[t] += x;
        __syncthreads();
    }
    int ex = sh[t] - s;
    if (base + 0 < NN) out[base + 0] = ex;
    if (base + 1 < NN) out[base + 1] = ex + v0;
    if (base + 2 < NN) out[base + 2] = ex + v0 + v1;
    if (base + 3 < NN) out[base + 3] = ex + v0 + v1 + v2;
    if (t == 255) bsum[blockIdx.x] = sh[255];
}

__global__ void k_scan2(int* bsum, int nb) {
    if (threadIdx.x == 0 && blockIdx.x == 0) {
        int run = 0;
        for (int i = 0; i < nb; ++i) { int t = bsum[i]; bsum[i] = run; run += t; }
    }
}

__global__ void k_scan3(int* __restrict__ rp, const int* __restrict__ bsum,
                        const int* __restrict__ cnt, float* __restrict__ dinv) {
    int i = blockIdx.x * 256 + threadIdx.x;
    if (i < NN) {
        rp[i] = rp[i] + bsum[i >> 10];
        dinv[i] = rsqrtf((float)(cnt[i] + 1));
    }
    if (i == 0) rp[NN] = NE;
}

// partial[p][s][il] -> absolute starting offset (in place)
__global__ void k_offs(int* __restrict__ partial, const int* __restrict__ rp) {
    int i = blockIdx.x * 256 + threadIdx.x;
    if (i >= NN) return;
    int p = i / RNG, il = i - p * RNG;
    int* q = partial + (p * SSL) * RNG + il;
    int run = rp[i];
#pragma unroll
    for (int s = 0; s < SSL; ++s) { int t = q[s * RNG]; q[s * RNG] = run; run += t; }
}

__global__ __launch_bounds__(256) void k_fillb(const int* __restrict__ dst32,
                                               const int* __restrict__ src32,
                                               const int* __restrict__ offs,
                                               int* __restrict__ col) {
    __shared__ int h[RNG];
    int p = blockIdx.x >> 5, s = blockIdx.x & 31;
    int t = threadIdx.x;
    const int* o = offs + blockIdx.x * RNG;
    for (int i = t * 4; i < RNG; i += 1024) *(int4*)(h + i) = *(const int4*)(o + i);
    __syncthreads();
    int base = s * NES;
    int lo = p * RNG;
    int nfull = NES & ~1023;
    for (int k = t * 4; k < nfull; k += 1024) {
        int4 d4 = *(const int4*)(dst32 + base + k);
        int4 s4 = *(const int4*)(src32 + base + k);
        int a;
        a = d4.x - lo; if ((unsigned)a < RNG) col[atomicAdd(&h[a], 1)] = s4.x;
        a = d4.y - lo; if ((unsigned)a < RNG) col[atomicAdd(&h[a], 1)] = s4.y;
        a = d4.z - lo; if ((unsigned)a < RNG) col[atomicAdd(&h[a], 1)] = s4.z;
        a = d4.w - lo; if ((unsigned)a < RNG) col[atomicAdd(&h[a], 1)] = s4.w;
    }
    for (int k = nfull + t; k < NES; k += 256) {
        int a = dst32[base + k] - lo;
        if ((unsigned)a < RNG) col[atomicAdd(&h[a], 1)] = src32[base + k];
    }
}

// ---------------- GEMM 128x128 (m97 structure): C = dinv[row]*(A@Wt^T) ----------------

#define GLL(g, l) __builtin_amdgcn_global_load_lds( \
    (const __attribute__((address_space(1))) unsigned int*)(g), \
    (__attribute__((address_space(3))) unsigned int*)(l), 16, 0, 0)

__global__ __launch_bounds__(256) void k_gemm128(const u16* __restrict__ A,
                                                 const u16* __restrict__ Wt,
                                                 const float* __restrict__ dinv,
                                                 u16* __restrict__ C,
                                                 int K) {
    __shared__ __align__(16) u16 As[128 * 32];
    __shared__ __align__(16) u16 Bs[128 * 32];
    int t = threadIdx.x;
    int bm = blockIdx.x, bn = blockIdx.y;
    int rowBase = bm * 128;
    int w = t >> 6, lane = t & 63;
    int wm = w >> 1, wn = w & 1;
    int lrow = lane & 15, lq = lane >> 4;

    f32x4 acc[4][4] = {};

    int r0 = t >> 2;
    int seg = (t & 3) * 8;
    int ar0 = rowBase + r0;       if (ar0 > NN - 1) ar0 = NN - 1;
    int ar1 = rowBase + 64 + r0;  if (ar1 > NN - 1) ar1 = NN - 1;
    const u16* a0p = A + (size_t)ar0 * K + seg;
    const u16* a1p = A + (size_t)ar1 * K + seg;
    const u16* b0p = Wt + (size_t)(bn * 128 + r0) * K + seg;
    const u16* b1p = Wt + (size_t)(bn * 128 + 64 + r0) * K + seg;
    u16* As0 = As + t * 8;
    u16* As1 = As + 2048 + t * 8;
    u16* Bs0 = Bs + t * 8;
    u16* Bs1 = Bs + 2048 + t * 8;

    int nK = K >> 5;
    for (int kt = 0; kt < nK; ++kt) {
        GLL(a0p, As0);
        GLL(a1p, As1);
        GLL(b0p, Bs0);
        GLL(b1p, Bs1);
        a0p += 32; a1p += 32; b0p += 32; b1p += 32;
        __syncthreads();
        s16x8 af[4], bf[4];
#pragma unroll
        for (int i = 0; i < 4; ++i)
            af[i] = *(const s16x8*)(As + (wm * 64 + i * 16 + lrow) * 32 + lq * 8);
#pragma unroll
        for (int j = 0; j < 4; ++j)
            bf[j] = *(const s16x8*)(Bs + (wn * 64 + j * 16 + lrow) * 32 + lq * 8);
#pragma unroll
        for (int i = 0; i < 4; ++i)
#pragma unroll
            for (int j = 0; j < 4; ++j)
                acc[i][j] = __builtin_amdgcn_mfma_f32_16x16x32_bf16(af[i], bf[j], acc[i][j], 0, 0, 0);
        __syncthreads();
    }

#pragma unroll
    for (int i = 0; i < 4; ++i) {
#pragma unroll
        for (int rr = 0; rr < 4; ++rr) {
            int row = rowBase + wm * 64 + i * 16 + lq * 4 + rr;
            if (row < NN) {
                float d = dinv[row];
#pragma unroll
                for (int j = 0; j < 4; ++j) {
                    int colg = bn * 128 + wn * 64 + j * 16 + lrow;
                    C[(size_t)row * HIDDEN + colg] = f2bf(acc[i][j][rr] * d);
                }
            }
        }
    }
}

// ---------------- GEMM 64x64 (conv5) ----------------
#define LDT 40

__global__ __launch_bounds__(256) void k_gemm64(const u16* __restrict__ A,
                                                const u16* __restrict__ Wt,
                                                const float* __restrict__ dinv,
                                                u16* __restrict__ C,
                                                int K, int Fstore) {
    __shared__ __align__(16) u16 As[64 * LDT];
    __shared__ __align__(16) u16 Bs[64 * LDT];
    int t = threadIdx.x;
    int bm = blockIdx.x, bn = blockIdx.y;
    int rowBase = bm * 64;
    int r = t >> 2;
    int cseg = (t & 3) * 8;
    int w = t >> 6;
    int wm = w >> 1, wn = w & 1;
    int lane = t & 63;
    int lrow = lane & 15;
    int lq = lane >> 4;
    f32x4 acc[2][2] = {};

    int nK = K >> 5;
    for (int kt = 0; kt < nK; ++kt) {
        int k0 = kt * 32;
        uint4 av = make_uint4(0, 0, 0, 0);
        int arow = rowBase + r;
        if (arow < NN) av = *(const uint4*)(A + (size_t)arow * K + k0 + cseg);
        *(uint4*)(As + r * LDT + cseg) = av;
        uint4 bv = *(const uint4*)(Wt + (size_t)(bn * 64 + r) * K + k0 + cseg);
        *(uint4*)(Bs + r * LDT + cseg) = bv;
        __syncthreads();

        s16x8 afr[2], bfr[2];
        afr[0] = *(const s16x8*)(As + (wm * 32 + lrow) * LDT + lq * 8);
        afr[1] = *(const s16x8*)(As + (wm * 32 + 16 + lrow) * LDT + lq * 8);
        bfr[0] = *(const s16x8*)(Bs + (wn * 32 + lrow) * LDT + lq * 8);
        bfr[1] = *(const s16x8*)(Bs + (wn * 32 + 16 + lrow) * LDT + lq * 8);
#pragma unroll
        for (int i = 0; i < 2; ++i)
#pragma unroll
            for (int j = 0; j < 2; ++j)
                acc[i][j] = __builtin_amdgcn_mfma_f32_16x16x32_bf16(afr[i], bfr[j], acc[i][j], 0, 0, 0);
        __syncthreads();
    }

#pragma unroll
    for (int ti = 0; ti < 2; ++ti)
#pragma unroll
        for (int tj = 0; tj < 2; ++tj)
#pragma unroll
            for (int rr = 0; rr < 4; ++rr) {
                int row = rowBase + wm * 32 + ti * 16 + lq * 4 + rr;
                int colg = bn * 64 + wn * 32 + tj * 16 + lrow;
                if (row < NN && colg < Fstore)
                    C[(size_t)row * Fstore + colg] = f2bf(acc[ti][tj][rr] * dinv[row]);
            }
}

// ---------------- aggregation F=256 ----------------
// one wave per row; half-wave per edge, 4x unroll (8 gathers in flight per wave)

__device__ __forceinline__ void acc8(float* a, uint4 v) {
    a[0] += bf2f((u16)(v.x & 0xffff)); a[1] += bf2f((u16)(v.x >> 16));
    a[2] += bf2f((u16)(v.y & 0xffff)); a[3] += bf2f((u16)(v.y >> 16));
    a[4] += bf2f((u16)(v.z & 0xffff)); a[5] += bf2f((u16)(v.z >> 16));
    a[6] += bf2f((u16)(v.w & 0xffff)); a[7] += bf2f((u16)(v.w >> 16));
}

__global__ __launch_bounds__(256) void k_agg(const u16* __restrict__ hs,
                                             const int* __restrict__ rp,
                                             const int* __restrict__ col,
                                             const float* __restrict__ dinv,
                                             const u16* __restrict__ bias,
                                             u16* __restrict__ out) {
    int row = blockIdx.x * 4 + (threadIdx.x >> 6);
    if (row >= NN) return;
    int lane = threadIdx.x & 63;
    int half = lane >> 5;
    int fb = (lane & 31) * 8;
    float a[8] = {0.f, 0.f, 0.f, 0.f, 0.f, 0.f, 0.f, 0.f};
    if (half == 0) acc8(a, *(const uint4*)(hs + (size_t)row * HIDDEN + fb));
    int p = rp[row] + half, p1 = rp[row + 1];
    for (; p + 6 < p1; p += 8) {
        int s0 = col[p], s1 = col[p + 2], s2 = col[p + 4], s3 = col[p + 6];
        uint4 v0 = *(const uint4*)(hs + (size_t)s0 * HIDDEN + fb);
        uint4 v1 = *(const uint4*)(hs + (size_t)s1 * HIDDEN + fb);
        uint4 v2 = *(const uint4*)(hs + (size_t)s2 * HIDDEN + fb);
        uint4 v3 = *(const uint4*)(hs + (size_t)s3 * HIDDEN + fb);
        acc8(a, v0);
        acc8(a, v1);
        acc8(a, v2);
        acc8(a, v3);
    }
    for (; p < p1; p += 2) {
        int s = col[p];
        acc8(a, *(const uint4*)(hs + (size_t)s * HIDDEN + fb));
    }
#pragma unroll
    for (int i = 0; i < 8; ++i) a[i] += __shfl_xor(a[i], 32);
    if (half == 0) {
        float d = dinv[row];
        uint4 bv = *(const uint4*)(bias + fb);
        float r0 = fmaxf(fmaf(d, a[0], bf2f((u16)(bv.x & 0xffff))), 0.f);
        float r1 = fmaxf(fmaf(d, a[1], bf2f((u16)(bv.x >> 16))), 0.f);
        float r2 = fmaxf(fmaf(d, a[2], bf2f((u16)(bv.y & 0xffff))), 0.f);
        float r3 = fmaxf(fmaf(d, a[3], bf2f((u16)(bv.y >> 16))), 0.f);
        float r4 = fmaxf(fmaf(d, a[4], bf2f((u16)(bv.z & 0xffff))), 0.f);
        float r5 = fmaxf(fmaf(d, a[5], bf2f((u16)(bv.z >> 16))), 0.f);
        float r6 = fmaxf(fmaf(d, a[6], bf2f((u16)(bv.w & 0xffff))), 0.f);
        float r7 = fmaxf(fmaf(d, a[7], bf2f((u16)(bv.w >> 16))), 0.f);
        uint4 o;
        o.x = (uint32_t)f2bf(r0) | ((uint32_t)f2bf(r1) << 16);
        o.y = (uint32_t)f2bf(r2) | ((uint32_t)f2bf(r3) << 16);
        o.z = (uint32_t)f2bf(r4) | ((uint32_t)f2bf(r5) << 16);
        o.w = (uint32_t)f2bf(r6) | ((uint32_t)f2bf(r7) << 16);
        *(uint4*)(out + (size_t)row * HIDDEN + fb) = o;
    }
}

// ---------------- last layer: aggregate F=40 + bias + log_softmax ----------------
__global__ __launch_bounds__(256) void k_agg5(const u16* __restrict__ hs,
                                              const int* __restrict__ rp,
                                              const int* __restrict__ col,
                                              const float* __restrict__ dinv,
                                              const u16* __restrict__ bias,
                                              void* __restrict__ out,
                                              const int* __restrict__ flags) {
    int row = blockIdx.x * 4 + (threadIdx.x >> 6);
    if (row >= NN) return;
    int lane = threadIdx.x & 63;
    bool act = lane < NCLS;
    float acc = 0.f;
    if (act) acc = bf2f(hs[(size_t)row * NCLS + lane]);
    int p = rp[row], p1 = rp[row + 1];
    for (; p + 1 < p1; p += 2) {
        int s0 = col[p], s1 = col[p + 1];
        if (act) {
            float v0 = bf2f(hs[(size_t)s0 * NCLS + lane]);
            float v1 = bf2f(hs[(size_t)s1 * NCLS + lane]);
            acc += v0 + v1;
        }
    }
    if (p < p1) {
        int s = col[p];
        if (act) acc += bf2f(hs[(size_t)s * NCLS + lane]);
    }
    float logit = act ? fmaf(dinv[row], acc, bf2f(bias[lane])) : -1e30f;
    float m = logit;
#pragma unroll
    for (int off = 32; off > 0; off >>= 1) m = fmaxf(m, __shfl_xor(m, off));
    float e = act ? __expf(logit - m) : 0.f;
    float ssum = e;
#pragma unroll
    for (int off = 32; off > 0; off >>= 1) ssum += __shfl_xor(ssum, off);
    if (act) {
        float r = logit - m - __logf(ssum);
        size_t idx = (size_t)row * NCLS + lane;
        if (flags[0]) ((float*)out)[idx] = r;
        else          ((u16*)out)[idx]   = f2bf(r);
    }
}

// ---------------- launch ----------------

extern "C" void kernel_launch(void* const* d_in, const int* in_sizes, int n_in,
                              void* d_out, int out_size, void* d_ws, size_t ws_size,
                              hipStream_t stream) {
    const void* x  = d_in[0];
    const int* ei  = (const int*)d_in[1];
    const void* W1 = d_in[2];
    const void* b1 = d_in[3];
    const void* W2 = d_in[4];
    const void* b2 = d_in[5];
    const void* W3 = d_in[6];
    const void* b3 = d_in[7];
    const void* W4 = d_in[8];
    const void* b4 = d_in[9];

    char* p = (char*)d_ws;
    auto alloc = [&](size_t b) -> char* {
        char* r = p;
        p += (b + 255) & ~(size_t)255;
        return r;
    };
    int*   flags = (int*)alloc(256);
    int*   cnt  = (int*)alloc((size_t)NN * 4);
    float* dinv = (float*)alloc((size_t)NN * 4);
    int*   rp   = (int*)alloc((size_t)(NN + 1) * 4);
    int*   col  = (int*)alloc((size_t)NE * 4);
    int*   bsum = (int*)alloc(4096);
    u16* xb  = (u16*)alloc((size_t)NN * FIN * 2);
    u16* W1t = (u16*)alloc((size_t)256 * 128 * 2);
    u16* W2t = (u16*)alloc((size_t)256 * 256 * 2);
    u16* W3t = (u16*)alloc((size_t)256 * 256 * 2);
    u16* W4t = (u16*)alloc((size_t)64 * 256 * 2);
    u16* bb1 = (u16*)alloc(512);
    u16* bb2 = (u16*)alloc(512);
    u16* bb3 = (u16*)alloc(512);
    u16* bb4 = (u16*)alloc(128);
    u16* bufA = (u16*)alloc((size_t)NN * HIDDEN * 2);
    u16* bufB = (u16*)alloc((size_t)NN * HIDDEN * 2);

    // CSR-build scratch aliased into bufA/bufB (used strictly before any conv)
    int* dst32   = (int*)bufA;                    // 6.4 MB
    int* src32   = dst32 + NE;                    // 6.4 MB
    int* partial = (int*)bufB;                    // PRNG*SSL*RNG*4 = 12.8 MB

    hipMemsetAsync(flags, 0, 256, stream);
    k_detect<<<1, 256, 0, stream>>>((const u16*)x, ei, flags);
    k_finalize_flags<<<1, 64, 0, stream>>>(flags);

    // CSR build (atomic-free at device scope)
    k_compact<<<(NE + 255) / 256, 256, 0, stream>>>(ei, dst32, src32, flags);
    k_histb<<<PRNG * SSL, 256, 0, stream>>>(dst32, partial);
    k_sumpart<<<(NN + 255) / 256, 256, 0, stream>>>(partial, cnt);
    k_scan1<<<(NN + 1023) / 1024, 256, 0, stream>>>(cnt, rp, bsum);
    k_scan2<<<1, 64, 0, stream>>>(bsum, (NN + 1023) / 1024);
    k_scan3<<<(NN + 255) / 256, 256, 0, stream>>>(rp, bsum, cnt, dinv);
    k_offs<<<(NN + 255) / 256, 256, 0, stream>>>(partial, rp);
    k_fillb<<<PRNG * SSL, 256, 0, stream>>>(dst32, src32, partial, col);

    // weights / inputs to bf16
    k_cvt<<<(NN * FIN + 255) / 256, 256, 0, stream>>>(x, xb, NN * FIN, flags);
    k_cvt_bias<<<1, 256, 0, stream>>>(b1, b2, b3, b4, bb1, bb2, bb3, bb4, flags);
    k_transpose_all<<<704, 256, 0, stream>>>(W1, W2, W3, W4, W1t, W2t, W3t, W4t, flags);

    dim3 g128((NN + 127) / 128, 2);
    dim3 aggGrid((NN + 3) / 4);

    // conv1: x @ W1 (K=128)
    k_gemm128<<<g128, 256, 0, stream>>>(xb, W1t, dinv, bufB, 128);
    k_agg<<<aggGrid, 256, 0, stream>>>(bufB, rp, col, dinv, bb1, bufA);
    // conv2: @ W2
    k_gemm128<<<g128, 256, 0, stream>>>(bufA, W2t, dinv, bufB, 256);
    k_agg<<<aggGrid, 256, 0, stream>>>(bufB, rp, col, dinv, bb2, bufA);
    // conv3: @ W2 (reused)
    k_gemm128<<<g128, 256, 0, stream>>>(bufA, W2t, dinv, bufB, 256);
    k_agg<<<aggGrid, 256, 0, stream>>>(bufB, rp, col, dinv, bb2, bufA);
    // conv4: @ W3
    k_gemm128<<<g128, 256, 0, stream>>>(bufA, W3t, dinv, bufB, 256);
    k_agg<<<aggGrid, 256, 0, stream>>>(bufB, rp, col, dinv, bb3, bufA);
    // conv5: @ W4 (Fpad=64, store 40) + fused log_softmax
    dim3 g64((NN + 63) / 64, 1);
    k_gemm64<<<g64, 256, 0, stream>>>(bufA, W4t, dinv, bufB, 256, 40);
    k_agg5<<<aggGrid, 256, 0, stream>>>(bufB, rp, col, dinv, bb4, d_out, flags);
}